// Round 10
// baseline (3482.479 us; speedup 1.0000x reference)
//
#include <hip/hip_runtime.h>
#include <math.h>

// Problem constants
constexpr int kB   = 32;     // batch
constexpr int kN   = 2048;   // raw points
constexpr int kG   = 128;    // groups (FPS centers)
constexpr int kM   = 32;     // group size (KNN)
constexpr int kC   = 384;    // trans dim
constexpr int kH   = 8;      // heads
constexpr int kHD  = 48;     // head dim
constexpr int kNT  = 129;    // tokens (CLS + groups)
constexpr int kMLP = 1536;
constexpr int kRows = kB * kNT; // 4128
constexpr int kGC  = 512;       // encoder groups per chunk
constexpr int kRC  = kGC * kM;  // encoder rows per chunk = 16384

typedef __attribute__((ext_vector_type(8))) short bf16x8;
typedef __attribute__((ext_vector_type(4))) float f32x4;

__device__ __forceinline__ unsigned short f2bf(float x) {
  unsigned u = __float_as_uint(x);
  unsigned r = (u + 0x7fffu + ((u >> 16) & 1u)) >> 16;
  return (unsigned short)r;
}
__device__ __forceinline__ float bf2f(unsigned short u) {
  return __uint_as_float(((unsigned)u) << 16);
}

// ---------------------------------------------------------------- FPS
// r8's exact 2-wave version (best measured: 120us, selection bit-exact,
// absmax-validated). 16 points/lane in registers; scalar arithmetic,
// contract off, (dx2+dy2)+dz2 order; stride-swizzled LDS cloud for the
// uniform winner-coordinate broadcast.
__global__ __launch_bounds__(128, 1) void fps_kernel(
    const float* __restrict__ pts, float* __restrict__ center)
{
  #pragma clang fp contract(off)
  __shared__ float sx[kN + 64], sy[kN + 64], sz[kN + 64];
  __shared__ float rvv[2];
  __shared__ int   rii[2];
  const int b = blockIdx.x, t = threadIdx.x;
  const int lane = t & 63, w = t >> 6;
  const float* P = pts + (size_t)b * kN * 3;
  float rx[16], ry[16], rz[16], rd[16];
  const int base = t * 16;
  #pragma unroll
  for (int j = 0; j < 16; ++j) {
    int i = base + j;
    float x = P[3*i], y = P[3*i+1], z = P[3*i+2];
    rx[j] = x; ry[j] = y; rz[j] = z; rd[j] = 1e10f;
    int ii = i + (i >> 5);           // swizzle: conflict-free, injective
    sx[ii] = x; sy[ii] = y; sz[ii] = z;
  }
  __syncthreads();
  int last = 0;
  float* cb = center + (size_t)b * kG * 3;
  for (int it = 0; it < kG; ++it) {
    int ls = last + (last >> 5);
    float lx = sx[ls], ly = sy[ls], lz = sz[ls];   // uniform broadcast
    if (t == 0) { cb[3*it] = lx; cb[3*it+1] = ly; cb[3*it+2] = lz; }
    float bestv = -1.0f; int besti = kN;
    #pragma unroll
    for (int j = 0; j < 16; ++j) {
      float dx = rx[j]-lx, dy = ry[j]-ly, dz = rz[j]-lz;
      float d = (dx*dx + dy*dy) + dz*dz;
      float nd = fminf(rd[j], d);
      rd[j] = nd;
      if (nd > bestv) { bestv = nd; besti = base + j; }
    }
    #pragma unroll
    for (int off = 1; off < 64; off <<= 1) {
      float vv = __shfl_xor(bestv, off);
      int   ii = __shfl_xor(besti, off);
      if (vv > bestv || (vv == bestv && ii < besti)) { bestv = vv; besti = ii; }
    }
    if (lane == 0) { rvv[w] = bestv; rii[w] = besti; }
    __syncthreads();
    float v0 = rvv[0], v1 = rvv[1];
    int   i0 = rii[0], i1 = rii[1];
    last = (v1 > v0) ? i1 : i0;      // tie -> i0 (wave0 owns lower indices)
    __syncthreads();
  }
}

// ------------------------------------------------------- RoPE cos/sin table
__global__ void rope_kernel(const float* __restrict__ center,
                            float* __restrict__ pcs, float* __restrict__ psn)
{
  int idx = blockIdx.x*256 + threadIdx.x;
  if (idx >= kB*kG*24) return;
  int p  = idx % 24;
  int bg = idx / 24;
  int axis = p >> 3, j = p & 7;
  float e  = (float)(2*j) / 16.0f;
  float fr = 1.0f / powf(100.0f, e);
  float ang = center[(size_t)bg*3 + axis] * fr;
  pcs[idx] = cosf(ang);
  psn[idx] = sinf(ang);
}

// ---------------------------------------------------------------- KNN
__global__ __launch_bounds__(256) void knn_kernel(
    const float* __restrict__ pts, const float* __restrict__ center,
    float* __restrict__ neigh)
{
  #pragma clang fp contract(off)
  __shared__ float sx[kN + kN/32], sy[kN + kN/32], sz[kN + kN/32];
  const int t = threadIdx.x;
  const int lane = t & 63, w = t >> 6;
  const int blk = blockIdx.x;          // 1024 blocks; 32 per batch, 4 groups each
  const int b = blk >> 5;
  const float* P = pts + (size_t)b * kN * 3;
  for (int i = t; i < kN; i += 256) {
    int ii = i + (i >> 5);
    sx[ii] = P[3*i]; sy[ii] = P[3*i+1]; sz[ii] = P[3*i+2];
  }
  __syncthreads();
  const int bg = b*kG + (blk & 31)*4 + w;
  const float cx = center[(size_t)bg*3+0];
  const float cy = center[(size_t)bg*3+1];
  const float cz = center[(size_t)bg*3+2];
  float rd[32];
  const int base = lane * 32;
  #pragma unroll
  for (int j = 0; j < 32; ++j) {
    int is = lane*33 + j;
    float dx = cx - sx[is], dy = cy - sy[is], dz = cz - sz[is];
    rd[j] = (dx*dx + dy*dy) + dz*dz;
  }
  float* ob = neigh + (size_t)bg * kM * 3;
  int lastWin = -1;
  for (int m = 0; m < kM; ++m) {
    float bestv = 3.0e38f; int besti = kN;
    #pragma unroll
    for (int j = 0; j < 32; ++j) {
      float v = rd[j];
      if (base + j == lastWin) v = 3.0e38f;
      rd[j] = v;
      if (v < bestv) { bestv = v; besti = base + j; }
    }
    #pragma unroll
    for (int off = 1; off < 64; off <<= 1) {
      float vv = __shfl_xor(bestv, off);
      int   i2 = __shfl_xor(besti, off);
      if (vv < bestv || (vv == bestv && i2 < besti)) { bestv = vv; besti = i2; }
    }
    lastWin = besti;
    if (lane == 0) {
      int is = besti + (besti >> 5);
      ob[3*m+0] = sx[is] - cx; ob[3*m+1] = sy[is] - cy; ob[3*m+2] = sz[is] - cz;
    }
  }
}

// ------------------------------------------------- weight cvt fp32 -> bf16
__global__ void wcvt_kernel(const float* __restrict__ s,
                            unsigned short* __restrict__ d, int n)
{
  int i = (blockIdx.x*256 + threadIdx.x)*8;
  if (i >= n) return;
  float4 a = *(const float4*)(s + i), b = *(const float4*)(s + i + 4);
  bf16x8 v;
  v[0]=(short)f2bf(a.x); v[1]=(short)f2bf(a.y); v[2]=(short)f2bf(a.z); v[3]=(short)f2bf(a.w);
  v[4]=(short)f2bf(b.x); v[5]=(short)f2bf(b.y); v[6]=(short)f2bf(b.z); v[7]=(short)f2bf(b.w);
  *(bf16x8*)(d + i) = v;
}

// per-layer fused conversion of qkv|proj|fc1|fc2 (1769472 elements total)
__global__ void wcvt4_kernel(const float* __restrict__ q, const float* __restrict__ p,
                             const float* __restrict__ f1, const float* __restrict__ f2,
                             unsigned short* __restrict__ d)
{
  int i = (blockIdx.x*256 + threadIdx.x)*8;   // grid sized exactly
  const float* s; int lo;
  if (i < 442368)       { s = q;  lo = i; }
  else if (i < 589824)  { s = p;  lo = i - 442368; }
  else if (i < 1179648) { s = f1; lo = i - 589824; }
  else                  { s = f2; lo = i - 1179648; }
  float4 a = *(const float4*)(s + lo), b = *(const float4*)(s + lo + 4);
  bf16x8 v;
  v[0]=(short)f2bf(a.x); v[1]=(short)f2bf(a.y); v[2]=(short)f2bf(a.z); v[3]=(short)f2bf(a.w);
  v[4]=(short)f2bf(b.x); v[5]=(short)f2bf(b.y); v[6]=(short)f2bf(b.z); v[7]=(short)f2bf(b.w);
  *(bf16x8*)(d + i) = v;
}

// ------------------------------------------------- encoder layer1 (3->128)
__global__ __launch_bounds__(256) void enc1_kernel(
    const float* __restrict__ neighC,
    const float* __restrict__ w1, const float* __restrict__ b1,
    const float* __restrict__ g1, const float* __restrict__ be1,
    unsigned short* __restrict__ f1c)
{
  const int t = threadIdx.x;
  const int r = blockIdx.x*2 + (t >> 7);
  const int c = t & 127;
  const float* nr = neighC + (size_t)r*3;
  float x0 = nr[0], x1 = nr[1], x2 = nr[2];
  float s = x0*w1[3*c] + x1*w1[3*c+1] + x2*w1[3*c+2] + b1[c];
  float v = fmaxf(s*g1[c] + be1[c], 0.0f);
  f1c[(size_t)r*128 + c] = f2bf(v);
}

// ------------------------------------------------- encoder fg pool (layer2 max)
__global__ __launch_bounds__(256) void pool2_kernel(
    const unsigned short* __restrict__ f2c, unsigned short* __restrict__ fgc)
{
  const int g = blockIdx.x, c = threadIdx.x;
  float mx = -3.0e38f;
  #pragma unroll 8
  for (int m = 0; m < kM; ++m)
    mx = fmaxf(mx, bf2f(f2c[((size_t)g*kM + m)*256 + c]));
  fgc[(size_t)g*256 + c] = f2bf(mx);
}

// ------------------------------------------------------------- MFMA GEMM
// Out[M,N] (+epilogue) = A[M,K](bf16,lda) @ B[N,K](bf16,ldb)^T
// Block tile BMxBN (BM=FM*32, BN=FN*32); BK=64; 256 thr = 4 waves (2x2).
// EPI: 0 bf16 plain | 1 bf16 +bias | 2 f32 +bias | 3 bf16 relu((v+base[r>>5])*g+be)
//      4 fused 32-row max-pool (+bias) -> tokens (FM==2) | 5 f32 res+v+bias | 6 bf16 gelu(v+bias)
template <int EPI, int FM, int FN>
__global__ __launch_bounds__(256) void mgemm_kernel(
    const unsigned short* __restrict__ A, int lda,
    const unsigned short* __restrict__ Bb, int ldb,
    void* __restrict__ Cv,
    const float* __restrict__ bias,
    const float* __restrict__ aux,       // res (EPI5) or base (EPI3)
    const float* __restrict__ gsc, const float* __restrict__ bsc,  // EPI3
    int Mm, int Nn, int Kk,
    float* __restrict__ poolOut, int poolG0)
{
  constexpr int BM = FM*32, BN = FN*32;
  __shared__ unsigned short As[BM][72];
  __shared__ unsigned short Bs[BN][72];
  const int t = threadIdx.x;
  const int m0 = blockIdx.x * BM;
  const int n0 = blockIdx.y * BN;
  const int w = t >> 6, lane = t & 63;
  const int wm = w >> 1, wn = w & 1;
  const int lr = lane & 15;
  const int lk = (lane >> 4) * 8;
  const int srow = t >> 3;          // 0..31
  const int skseg = (t & 7) * 8;    // 0..56
  f32x4 acc[FM][FN] = {};
  for (int k0 = 0; k0 < Kk; k0 += 64) {
    #pragma unroll
    for (int p = 0; p < BM/32; ++p) {
      int r = p*32 + srow;
      int gr = m0 + r;
      bf16x8 av = {};
      if (gr < Mm) av = *(const bf16x8*)(A + (size_t)gr*lda + k0 + skseg);
      *(bf16x8*)(&As[r][skseg]) = av;
    }
    #pragma unroll
    for (int p = 0; p < BN/32; ++p) {
      int r = p*32 + srow;
      bf16x8 bv = *(const bf16x8*)(Bb + (size_t)(n0 + r)*ldb + k0 + skseg);
      *(bf16x8*)(&Bs[r][skseg]) = bv;
    }
    __syncthreads();
    #pragma unroll
    for (int kk = 0; kk < 64; kk += 32) {
      bf16x8 af[FM], bf[FN];
      #pragma unroll
      for (int i = 0; i < FM; ++i)
        af[i] = *(const bf16x8*)(&As[wm*(FM*16) + i*16 + lr][kk + lk]);
      #pragma unroll
      for (int i = 0; i < FN; ++i)
        bf[i] = *(const bf16x8*)(&Bs[wn*(FN*16) + i*16 + lr][kk + lk]);
      #pragma unroll
      for (int i = 0; i < FM; ++i)
        #pragma unroll
        for (int j = 0; j < FN; ++j)
          acc[i][j] = __builtin_amdgcn_mfma_f32_16x16x32_bf16(af[i], bf[j], acc[i][j], 0, 0, 0);
    }
    __syncthreads();
  }

  if constexpr (EPI == 4) {
    // fused max-pool over the wave's 32-row group (FM==2, Mm%64==0)
    #pragma unroll
    for (int ni = 0; ni < FN; ++ni) {
      int cc = n0 + wn*(FN*16) + ni*16 + lr;
      float mx = -3.0e38f;
      #pragma unroll
      for (int mi = 0; mi < FM; ++mi)
        #pragma unroll
        for (int j = 0; j < 4; ++j)
          mx = fmaxf(mx, acc[mi][ni][j]);
      mx = fmaxf(mx, __shfl_xor(mx, 16));
      mx = fmaxf(mx, __shfl_xor(mx, 32));
      if ((lane >> 4) == 0) {
        int ggl = poolG0 + (m0 >> 5) + wm;
        int b = ggl >> 7, g = ggl & 127;
        poolOut[((size_t)b*kNT + 1 + g)*kC + cc] = mx + bias[cc];
      }
    }
    return;
  }

  #pragma unroll
  for (int mi = 0; mi < FM; ++mi) {
    #pragma unroll
    for (int j = 0; j < 4; ++j) {
      int r = m0 + wm*(FM*16) + mi*16 + (lane >> 4)*4 + j;
      if (r < Mm) {
        #pragma unroll
        for (int ni = 0; ni < FN; ++ni) {
          int cc = n0 + wn*(FN*16) + ni*16 + lr;
          float v = acc[mi][ni][j];
          size_t o = (size_t)r*Nn + cc;
          if constexpr (EPI == 0) {
            ((unsigned short*)Cv)[o] = f2bf(v);
          } else if constexpr (EPI == 1) {
            ((unsigned short*)Cv)[o] = f2bf(v + bias[cc]);
          } else if constexpr (EPI == 2) {
            ((float*)Cv)[o] = v + bias[cc];
          } else if constexpr (EPI == 3) {
            float u = (v + aux[(size_t)(r >> 5)*Nn + cc])*gsc[cc] + bsc[cc];
            ((unsigned short*)Cv)[o] = f2bf(fmaxf(u, 0.0f));
          } else if constexpr (EPI == 5) {
            ((float*)Cv)[o] = aux[o] + v + bias[cc];
          } else {
            float u = v + bias[cc];
            ((unsigned short*)Cv)[o] = f2bf(0.5f*u*(1.0f + erff(u*0.70710678118654752440f)));
          }
        }
      }
    }
  }
}

// ----------------------------------------------------------- CLS token init
__global__ void cls_kernel(const float* __restrict__ ct, const float* __restrict__ cp,
                           float* __restrict__ x)
{
  int idx = blockIdx.x*256 + threadIdx.x;
  if (idx >= kB*kC) return;
  int b = idx / kC, c = idx % kC;
  x[(size_t)b*kNT*kC + c] = ct[c] + cp[c];
}

// ------------------------------------------------------------- LayerNorm
template <int OUTBF>
__global__ __launch_bounds__(256) void ln_kernel(
    const float* __restrict__ in, void* __restrict__ outv,
    const float* __restrict__ g, const float* __restrict__ bb)
{
  const int t = threadIdx.x;
  const int lane = t & 63;
  const int row = blockIdx.x*4 + (t >> 6);
  const float* p = in + (size_t)row*kC;
  float v[6];
  #pragma unroll
  for (int k = 0; k < 6; ++k) v[k] = p[k*64 + lane];
  float s = 0.f;
  #pragma unroll
  for (int k = 0; k < 6; ++k) s += v[k];
  #pragma unroll
  for (int off = 1; off < 64; off <<= 1) s += __shfl_xor(s, off);
  float mean = s / 384.0f;
  float vs = 0.f;
  #pragma unroll
  for (int k = 0; k < 6; ++k) { float d = v[k]-mean; vs += d*d; }
  #pragma unroll
  for (int off = 1; off < 64; off <<= 1) vs += __shfl_xor(vs, off);
  float r = rsqrtf(vs / 384.0f + 1e-5f);
  #pragma unroll
  for (int k = 0; k < 6; ++k) {
    int c = k*64 + lane;
    float o = (v[k]-mean)*r*g[c] + bb[c];
    if constexpr (OUTBF) ((unsigned short*)outv)[(size_t)row*kC + c] = f2bf(o);
    else                 ((float*)outv)[(size_t)row*kC + c] = o;
  }
}

// ------------------------------------------------------------- attention
// One block per (b,h), 1024 thr = 16 waves (was 8): staging strided over
// 1024 threads, 16 query rows in flight -> 2x latency hiding for a kernel
// that r7/r9 counters proved latency-bound (VALUBusy 6%, MfmaUtil 0,
// HBM 1.2%, bank-conflict fix changed nothing). Per-row arithmetic and
// staging expressions identical -> bit-exact. ks rows padded to 52 floats
// (8-way instead of 32-way conflicts, measured 36x conflict drop).
__global__ __launch_bounds__(1024) void attn_kernel(
    const unsigned short* __restrict__ qkv, const float* __restrict__ pcs,
    const float* __restrict__ psn, const float* __restrict__ gth,
    unsigned short* __restrict__ o)
{
  __shared__ float qs[kNT][kHD];
  __shared__ float ks[kNT][52];
  __shared__ float vls[kNT][kHD];
  __shared__ float gcs[24], gss[24];
  __shared__ float ps[16][132];
  const int t = threadIdx.x;
  const int bh = blockIdx.x;
  const int b = bh >> 3, hh = bh & 7;
  if (t < 24) { float th = gth[hh*24 + t]; gcs[t] = cosf(th); gss[t] = sinf(th); }
  __syncthreads();
  for (int idx = t; idx < kNT*24; idx += 1024) {
    int n = idx / 24, p = idx % 24;
    const unsigned short* base = qkv + ((size_t)(b*kNT + n))*1152 + hh*kHD + 2*p;
    float q0 = bf2f(base[0]),   q1 = bf2f(base[1]);
    float k0 = bf2f(base[384]), k1 = bf2f(base[385]);
    float v0 = bf2f(base[768]), v1 = bf2f(base[769]);
    float cg = gcs[p], sg = gss[p];
    float qr = q0*cg - q1*sg, qi = q0*sg + q1*cg;
    float kr = k0*cg - k1*sg, ki = k0*sg + k1*cg;
    if (n > 0) {
      size_t pi = ((size_t)b*kG + (n-1))*24 + p;
      float pc = pcs[pi], pv = psn[pi];
      float tq = qr*pc - qi*pv; qi = qr*pv + qi*pc; qr = tq;
      float tk = kr*pc - ki*pv; ki = kr*pv + ki*pc; kr = tk;
    }
    qs[n][2*p] = qr; qs[n][2*p+1] = qi;
    ks[n][2*p] = kr; ks[n][2*p+1] = ki;
    vls[n][2*p] = v0; vls[n][2*p+1] = v1;
  }
  __syncthreads();
  const int lane = t & 63, w = t >> 6;
  for (int r = w; r < kNT; r += 16) {
    float4 q[12];
    #pragma unroll
    for (int d = 0; d < 12; ++d) q[d] = *(const float4*)(&qs[r][d*4]);
    float sv[3];
    float mx = -3.0e38f;
    #pragma unroll
    for (int ji = 0; ji < 3; ++ji) {
      int j = ji*64 + lane;
      float s = -3.0e38f;
      if (j < kNT) {
        float a0 = 0.f, a1 = 0.f;
        #pragma unroll
        for (int d = 0; d < 12; d += 2) {
          float4 k0v = *(const float4*)(&ks[j][d*4]);
          float4 k1v = *(const float4*)(&ks[j][d*4+4]);
          a0 += q[d].x*k0v.x + q[d].y*k0v.y + q[d].z*k0v.z + q[d].w*k0v.w;
          a1 += q[d+1].x*k1v.x + q[d+1].y*k1v.y + q[d+1].z*k1v.z + q[d+1].w*k1v.w;
        }
        s = (a0 + a1) * 0.14433756729740643f;
      }
      sv[ji] = s;
      mx = fmaxf(mx, s);
    }
    #pragma unroll
    for (int off = 1; off < 64; off <<= 1) mx = fmaxf(mx, __shfl_xor(mx, off));
    float sum = 0.f;
    #pragma unroll
    for (int ji = 0; ji < 3; ++ji) {
      int j = ji*64 + lane;
      if (j < kNT) { float e = expf(sv[ji] - mx); ps[w][j] = e; sum += e; }
    }
    #pragma unroll
    for (int off = 1; off < 64; off <<= 1) sum += __shfl_xor(sum, off);
    if (lane < kHD) {
      float ac0 = 0.f, ac1 = 0.f, ac2 = 0.f, ac3 = 0.f;
      for (int j4 = 0; j4 < 128; j4 += 16) {
        float4 p0 = *(const float4*)(&ps[w][j4]);
        float4 p1 = *(const float4*)(&ps[w][j4+4]);
        float4 p2 = *(const float4*)(&ps[w][j4+8]);
        float4 p3 = *(const float4*)(&ps[w][j4+12]);
        ac0 += p0.x*vls[j4+0][lane] + p0.y*vls[j4+1][lane]
             + p0.z*vls[j4+2][lane] + p0.w*vls[j4+3][lane];
        ac1 += p1.x*vls[j4+4][lane] + p1.y*vls[j4+5][lane]
             + p1.z*vls[j4+6][lane] + p1.w*vls[j4+7][lane];
        ac2 += p2.x*vls[j4+8][lane] + p2.y*vls[j4+9][lane]
             + p2.z*vls[j4+10][lane] + p2.w*vls[j4+11][lane];
        ac3 += p3.x*vls[j4+12][lane] + p3.y*vls[j4+13][lane]
             + p3.z*vls[j4+14][lane] + p3.w*vls[j4+15][lane];
      }
      float accv = ((ac0 + ac1) + (ac2 + ac3)) + ps[w][128]*vls[128][lane];
      o[((size_t)(b*kNT + r))*kC + hh*kHD + lane] = f2bf(accv / sum);
    }
  }
}

// ------------------------------------------------------------- head
__global__ __launch_bounds__(256) void head_kernel(
    const float* __restrict__ xf,
    const float* __restrict__ hw1, const float* __restrict__ hb1,
    const float* __restrict__ hg1, const float* __restrict__ hbe1,
    const float* __restrict__ hw2, const float* __restrict__ hb2,
    const float* __restrict__ hg2, const float* __restrict__ hbe2,
    const float* __restrict__ hw3, const float* __restrict__ hb3,
    float* __restrict__ out)
{
  __shared__ float f[768];
  __shared__ float h1[256], h2[256];
  const int t = threadIdx.x;
  const int b = blockIdx.x;
  const float* xb = xf + (size_t)b*kNT*kC;
  for (int c = t; c < kC; c += 256) {
    f[c] = xb[c];
    float mx = -3.0e38f;
    for (int n = 1; n < kNT; ++n) mx = fmaxf(mx, xb[(size_t)n*kC + c]);
    f[kC + c] = mx;
  }
  __syncthreads();
  {
    float acc = hb1[t];
    for (int k = 0; k < 768; k += 4) {
      float4 wv = *(const float4*)(hw1 + (size_t)t*768 + k);
      float4 fv = *(const float4*)(&f[k]);
      acc += fv.x*wv.x + fv.y*wv.y + fv.z*wv.z + fv.w*wv.w;
    }
    h1[t] = fmaxf(acc*hg1[t] + hbe1[t], 0.0f);
  }
  __syncthreads();
  {
    float acc = hb2[t];
    for (int k = 0; k < 256; k += 4) {
      float4 wv = *(const float4*)(hw2 + (size_t)t*256 + k);
      float4 fv = *(const float4*)(&h1[k]);
      acc += fv.x*wv.x + fv.y*wv.y + fv.z*wv.z + fv.w*wv.w;
    }
    h2[t] = fmaxf(acc*hg2[t] + hbe2[t], 0.0f);
  }
  __syncthreads();
  if (t < 40) {
    float acc = hb3[t];
    for (int k = 0; k < 256; k += 4) {
      float4 wv = *(const float4*)(hw3 + (size_t)t*256 + k);
      float4 fv = *(const float4*)(&h2[k]);
      acc += fv.x*wv.x + fv.y*wv.y + fv.z*wv.z + fv.w*wv.w;
    }
    out[(size_t)b*40 + t] = acc;
  }
}

// ------------------------------------------------------------- launch
extern "C" void kernel_launch(void* const* d_in, const int* in_sizes, int n_in,
                              void* d_out, int out_size, void* d_ws, size_t ws_size,
                              hipStream_t stream) {
  const float* pts     = (const float*)d_in[0];
  const float* enc_w1  = (const float*)d_in[1];
  const float* enc_b1  = (const float*)d_in[2];
  const float* enc_g1  = (const float*)d_in[3];
  const float* enc_be1 = (const float*)d_in[4];
  const float* enc_w2  = (const float*)d_in[5];
  const float* enc_b2  = (const float*)d_in[6];
  const float* enc_w3  = (const float*)d_in[7];
  const float* enc_b3  = (const float*)d_in[8];
  const float* enc_g2  = (const float*)d_in[9];
  const float* enc_be2 = (const float*)d_in[10];
  const float* enc_w4  = (const float*)d_in[11];
  const float* enc_b4  = (const float*)d_in[12];
  const float* cls_tok = (const float*)d_in[13];
  const float* cls_pos = (const float*)d_in[14];
  const float* ln1_g   = (const float*)d_in[15];
  const float* ln1_b   = (const float*)d_in[16];
  const float* qkv_w   = (const float*)d_in[17];
  const float* givens  = (const float*)d_in[18];
  const float* proj_w  = (const float*)d_in[19];
  const float* proj_b  = (const float*)d_in[20];
  const float* ln2_g   = (const float*)d_in[21];
  const float* ln2_b   = (const float*)d_in[22];
  const float* fc1_w   = (const float*)d_in[23];
  const float* fc1_b   = (const float*)d_in[24];
  const float* fc2_w   = (const float*)d_in[25];
  const float* fc2_b   = (const float*)d_in[26];
  const float* norm_g  = (const float*)d_in[27];
  const float* norm_b  = (const float*)d_in[28];
  const float* hw1     = (const float*)d_in[29];
  const float* hb1     = (const float*)d_in[30];
  const float* hg1     = (const float*)d_in[31];
  const float* hbe1    = (const float*)d_in[32];
  const float* hw2     = (const float*)d_in[33];
  const float* hb2     = (const float*)d_in[34];
  const float* hg2     = (const float*)d_in[35];
  const float* hbe2    = (const float*)d_in[36];
  const float* hw3     = (const float*)d_in[37];
  const float* hb3     = (const float*)d_in[38];

  constexpr size_t kWL = 1769472ull;          // per-layer bf16 weight elements
  char* wsb = (char*)d_ws;
  size_t off = 0;
  float* center = (float*)(wsb + off); off += (size_t)kB*kG*3*4;
  float* pcs    = (float*)(wsb + off); off += (size_t)kB*kG*24*4;
  float* psn    = (float*)(wsb + off); off += (size_t)kB*kG*24*4;
  float* neigh  = (float*)(wsb + off); off += (size_t)kB*kG*kM*3*4;
  float* xbuf   = (float*)(wsb + off); off += (size_t)kRows*kC*4;
  unsigned short* encwb = (unsigned short*)(wsb + off); off += 491520ull*2;
  unsigned short* wlbf  = (unsigned short*)(wsb + off);
  const size_t scratchNeed = 16777216ull + 8388608ull + 262144ull + 1048576ull;
  const bool bigws = ws_size >= off + 12*kWL*2 + scratchNeed;
  off += (bigws ? 12*kWL*2 : kWL*2);
  char* scratch = wsb + off;
  // encoder view of scratch (f1c aliases f3c region: disjoint lifetimes)
  unsigned short* f3c   = (unsigned short*)(scratch);
  unsigned short* f1c   = (unsigned short*)(scratch);
  unsigned short* f2c   = (unsigned short*)(scratch + 16777216);
  unsigned short* fgc   = (unsigned short*)(scratch + 16777216 + 8388608);
  float*          basec = (float*)(scratch + 16777216 + 8388608 + 262144);
  // transformer view of scratch (hbuf + qkvb + attnob; mlpb aliases)
  unsigned short* hbuf   = (unsigned short*)(scratch);
  unsigned short* qkvb   = (unsigned short*)(scratch + 3170304);
  unsigned short* attnob = (unsigned short*)(scratch + 3170304 + 9510912);
  unsigned short* mlpb   = (unsigned short*)(scratch + 3170304);
  float*          flnb   = (float*)(scratch + 3170304);  // post-loop, qkvb dead

  const unsigned short* encw2 = encwb;
  const unsigned short* encw3 = encwb + 32768;
  const unsigned short* encw4 = encwb + 32768 + 262144;

  fps_kernel<<<kB, 128, 0, stream>>>(pts, center);
  rope_kernel<<<(kB*kG*24 + 255)/256, 256, 0, stream>>>(center, pcs, psn);
  knn_kernel<<<kB*kG/4, 256, 0, stream>>>(pts, center, neigh);

  // weight caches
  wcvt_kernel<<<32768/8/256, 256, 0, stream>>>(enc_w2, (unsigned short*)encw2, 32768);
  wcvt_kernel<<<262144/8/256, 256, 0, stream>>>(enc_w3, (unsigned short*)encw3, 262144);
  wcvt_kernel<<<196608/8/256, 256, 0, stream>>>(enc_w4, (unsigned short*)encw4, 196608);
  if (bigws) {
    for (int l = 0; l < 12; ++l)
      wcvt4_kernel<<<864, 256, 0, stream>>>(
          qkv_w + (size_t)l*442368, proj_w + (size_t)l*147456,
          fc1_w + (size_t)l*589824, fc2_w + (size_t)l*589824, wlbf + (size_t)l*kWL);
  }

  // ---- encoder: 8 chunks of 512 groups (16384 rows) ----
  for (int c = 0; c < 8; ++c) {
    const float* nc = neigh + (size_t)c*kRC*3;
    enc1_kernel<<<kRC/2, 256, 0, stream>>>(nc, enc_w1, enc_b1, enc_g1, enc_be1, f1c);
    mgemm_kernel<1,2,2><<<dim3(kRC/64, 4), 256, 0, stream>>>(
        f1c, 128, encw2, 128, f2c, enc_b2, nullptr, nullptr, nullptr,
        kRC, 256, 128, nullptr, 0);
    pool2_kernel<<<kGC, 256, 0, stream>>>(f2c, fgc);
    mgemm_kernel<2,2,2><<<dim3(kGC/64, 8), 256, 0, stream>>>(
        fgc, 256, encw3, 512, basec, enc_b3, nullptr, nullptr, nullptr,
        kGC, 512, 256, nullptr, 0);
    mgemm_kernel<3,2,2><<<dim3(kRC/64, 8), 256, 0, stream>>>(
        f2c, 256, encw3 + 256, 512, f3c, nullptr, basec, enc_g2, enc_be2,
        kRC, 512, 256, nullptr, 0);
    mgemm_kernel<4,2,2><<<dim3(kRC/64, 6), 256, 0, stream>>>(
        f3c, 512, encw4, 512, nullptr, enc_b4, nullptr, nullptr, nullptr,
        kRC, 384, 512, xbuf, c*kGC);
  }
  cls_kernel<<<(kB*kC + 255)/256, 256, 0, stream>>>(cls_tok, cls_pos, xbuf);

  const int lnGrid = kRows/4;
  for (int l = 0; l < 12; ++l) {
    unsigned short* wl = wlbf + (bigws ? (size_t)l*kWL : 0);
    if (!bigws)
      wcvt4_kernel<<<864, 256, 0, stream>>>(
          qkv_w + (size_t)l*442368, proj_w + (size_t)l*147456,
          fc1_w + (size_t)l*589824, fc2_w + (size_t)l*589824, wl);
    const unsigned short* wq  = wl;
    const unsigned short* wp  = wl + 442368;
    const unsigned short* w1f = wl + 589824;
    const unsigned short* w2f = wl + 1179648;
    ln_kernel<1><<<lnGrid, 256, 0, stream>>>(xbuf, hbuf, ln1_g + l*kC, ln1_b + l*kC);
    mgemm_kernel<0,2,2><<<dim3(65, 18), 256, 0, stream>>>(
        hbuf, kC, wq, kC, qkvb, nullptr, nullptr, nullptr, nullptr,
        kRows, 1152, kC, nullptr, 0);
    attn_kernel<<<kB*kH, 1024, 0, stream>>>(qkvb, pcs, psn, givens + (size_t)l*kH*24, attnob);
    mgemm_kernel<5,2,2><<<dim3(65, 6), 256, 0, stream>>>(
        attnob, kC, wp, kC, xbuf, proj_b + l*kC, xbuf, nullptr, nullptr,
        kRows, kC, kC, nullptr, 0);
    ln_kernel<1><<<lnGrid, 256, 0, stream>>>(xbuf, hbuf, ln2_g + l*kC, ln2_b + l*kC);
    mgemm_kernel<6,2,2><<<dim3(65, 24), 256, 0, stream>>>(
        hbuf, kC, w1f, kC, mlpb, fc1_b + l*kMLP, nullptr, nullptr, nullptr,
        kRows, kMLP, kC, nullptr, 0);
    mgemm_kernel<5,2,2><<<dim3(65, 6), 256, 0, stream>>>(
        mlpb, kMLP, w2f, kMLP, xbuf, fc2_b + l*kC, xbuf, nullptr, nullptr,
        kRows, kC, kMLP, nullptr, 0);
  }
  ln_kernel<0><<<lnGrid, 256, 0, stream>>>(xbuf, flnb, norm_g, norm_b);
  head_kernel<<<kB, 256, 0, stream>>>(flnb,
      hw1, hb1, hg1, hbe1, hw2, hb2, hg2, hbe2, hw3, hb3, (float*)d_out);
}

// Round 11
// 2347.374 us; speedup vs baseline: 1.4836x; 1.4836x over previous
//
#include <hip/hip_runtime.h>
#include <math.h>

// Problem constants
constexpr int kB   = 32;     // batch
constexpr int kN   = 2048;   // raw points
constexpr int kG   = 128;    // groups (FPS centers)
constexpr int kM   = 32;     // group size (KNN)
constexpr int kC   = 384;    // trans dim
constexpr int kH   = 8;      // heads
constexpr int kHD  = 48;     // head dim
constexpr int kNT  = 129;    // tokens (CLS + groups)
constexpr int kMLP = 1536;
constexpr int kRows = kB * kNT; // 4128
constexpr int kGC  = 512;       // encoder groups per chunk
constexpr int kRC  = kGC * kM;  // encoder rows per chunk = 16384

typedef __attribute__((ext_vector_type(8))) short bf16x8;
typedef __attribute__((ext_vector_type(4))) float f32x4;

__device__ __forceinline__ unsigned short f2bf(float x) {
  unsigned u = __float_as_uint(x);
  unsigned r = (u + 0x7fffu + ((u >> 16) & 1u)) >> 16;
  return (unsigned short)r;
}
__device__ __forceinline__ float bf2f(unsigned short u) {
  return __uint_as_float(((unsigned)u) << 16);
}

// ---------------------------------------------------------------- FPS
// r8's exact 2-wave version (best measured: 120us, selection bit-exact,
// absmax-validated).
__global__ __launch_bounds__(128, 1) void fps_kernel(
    const float* __restrict__ pts, float* __restrict__ center)
{
  #pragma clang fp contract(off)
  __shared__ float sx[kN + 64], sy[kN + 64], sz[kN + 64];
  __shared__ float rvv[2];
  __shared__ int   rii[2];
  const int b = blockIdx.x, t = threadIdx.x;
  const int lane = t & 63, w = t >> 6;
  const float* P = pts + (size_t)b * kN * 3;
  float rx[16], ry[16], rz[16], rd[16];
  const int base = t * 16;
  #pragma unroll
  for (int j = 0; j < 16; ++j) {
    int i = base + j;
    float x = P[3*i], y = P[3*i+1], z = P[3*i+2];
    rx[j] = x; ry[j] = y; rz[j] = z; rd[j] = 1e10f;
    int ii = i + (i >> 5);           // swizzle: conflict-free, injective
    sx[ii] = x; sy[ii] = y; sz[ii] = z;
  }
  __syncthreads();
  int last = 0;
  float* cb = center + (size_t)b * kG * 3;
  for (int it = 0; it < kG; ++it) {
    int ls = last + (last >> 5);
    float lx = sx[ls], ly = sy[ls], lz = sz[ls];   // uniform broadcast
    if (t == 0) { cb[3*it] = lx; cb[3*it+1] = ly; cb[3*it+2] = lz; }
    float bestv = -1.0f; int besti = kN;
    #pragma unroll
    for (int j = 0; j < 16; ++j) {
      float dx = rx[j]-lx, dy = ry[j]-ly, dz = rz[j]-lz;
      float d = (dx*dx + dy*dy) + dz*dz;
      float nd = fminf(rd[j], d);
      rd[j] = nd;
      if (nd > bestv) { bestv = nd; besti = base + j; }
    }
    #pragma unroll
    for (int off = 1; off < 64; off <<= 1) {
      float vv = __shfl_xor(bestv, off);
      int   ii = __shfl_xor(besti, off);
      if (vv > bestv || (vv == bestv && ii < besti)) { bestv = vv; besti = ii; }
    }
    if (lane == 0) { rvv[w] = bestv; rii[w] = besti; }
    __syncthreads();
    float v0 = rvv[0], v1 = rvv[1];
    int   i0 = rii[0], i1 = rii[1];
    last = (v1 > v0) ? i1 : i0;      // tie -> i0 (wave0 owns lower indices)
    __syncthreads();
  }
}

// ------------------------------------------------------- RoPE cos/sin table
__global__ void rope_kernel(const float* __restrict__ center,
                            float* __restrict__ pcs, float* __restrict__ psn)
{
  int idx = blockIdx.x*256 + threadIdx.x;
  if (idx >= kB*kG*24) return;
  int p  = idx % 24;
  int bg = idx / 24;
  int axis = p >> 3, j = p & 7;
  float e  = (float)(2*j) / 16.0f;
  float fr = 1.0f / powf(100.0f, e);
  float ang = center[(size_t)bg*3 + axis] * fr;
  pcs[idx] = cosf(ang);
  psn[idx] = sinf(ang);
}

// ---------------------------------------------------------------- KNN
__global__ __launch_bounds__(256) void knn_kernel(
    const float* __restrict__ pts, const float* __restrict__ center,
    float* __restrict__ neigh)
{
  #pragma clang fp contract(off)
  __shared__ float sx[kN + kN/32], sy[kN + kN/32], sz[kN + kN/32];
  const int t = threadIdx.x;
  const int lane = t & 63, w = t >> 6;
  const int blk = blockIdx.x;          // 1024 blocks; 32 per batch, 4 groups each
  const int b = blk >> 5;
  const float* P = pts + (size_t)b * kN * 3;
  for (int i = t; i < kN; i += 256) {
    int ii = i + (i >> 5);
    sx[ii] = P[3*i]; sy[ii] = P[3*i+1]; sz[ii] = P[3*i+2];
  }
  __syncthreads();
  const int bg = b*kG + (blk & 31)*4 + w;
  const float cx = center[(size_t)bg*3+0];
  const float cy = center[(size_t)bg*3+1];
  const float cz = center[(size_t)bg*3+2];
  float rd[32];
  const int base = lane * 32;
  #pragma unroll
  for (int j = 0; j < 32; ++j) {
    int is = lane*33 + j;
    float dx = cx - sx[is], dy = cy - sy[is], dz = cz - sz[is];
    rd[j] = (dx*dx + dy*dy) + dz*dz;
  }
  float* ob = neigh + (size_t)bg * kM * 3;
  int lastWin = -1;
  for (int m = 0; m < kM; ++m) {
    float bestv = 3.0e38f; int besti = kN;
    #pragma unroll
    for (int j = 0; j < 32; ++j) {
      float v = rd[j];
      if (base + j == lastWin) v = 3.0e38f;
      rd[j] = v;
      if (v < bestv) { bestv = v; besti = base + j; }
    }
    #pragma unroll
    for (int off = 1; off < 64; off <<= 1) {
      float vv = __shfl_xor(bestv, off);
      int   i2 = __shfl_xor(besti, off);
      if (vv < bestv || (vv == bestv && i2 < besti)) { bestv = vv; besti = i2; }
    }
    lastWin = besti;
    if (lane == 0) {
      int is = besti + (besti >> 5);
      ob[3*m+0] = sx[is] - cx; ob[3*m+1] = sy[is] - cy; ob[3*m+2] = sz[is] - cz;
    }
  }
}

// ------------------------------------------------- weight cvt fp32 -> bf16
__global__ void wcvt_kernel(const float* __restrict__ s,
                            unsigned short* __restrict__ d, int n)
{
  int i = (blockIdx.x*256 + threadIdx.x)*8;
  if (i >= n) return;
  float4 a = *(const float4*)(s + i), b = *(const float4*)(s + i + 4);
  bf16x8 v;
  v[0]=(short)f2bf(a.x); v[1]=(short)f2bf(a.y); v[2]=(short)f2bf(a.z); v[3]=(short)f2bf(a.w);
  v[4]=(short)f2bf(b.x); v[5]=(short)f2bf(b.y); v[6]=(short)f2bf(b.z); v[7]=(short)f2bf(b.w);
  *(bf16x8*)(d + i) = v;
}

// per-layer fused conversion of qkv|proj|fc1|fc2 (1769472 elements total)
__global__ void wcvt4_kernel(const float* __restrict__ q, const float* __restrict__ p,
                             const float* __restrict__ f1, const float* __restrict__ f2,
                             unsigned short* __restrict__ d)
{
  int i = (blockIdx.x*256 + threadIdx.x)*8;   // grid sized exactly
  const float* s; int lo;
  if (i < 442368)       { s = q;  lo = i; }
  else if (i < 589824)  { s = p;  lo = i - 442368; }
  else if (i < 1179648) { s = f1; lo = i - 589824; }
  else                  { s = f2; lo = i - 1179648; }
  float4 a = *(const float4*)(s + lo), b = *(const float4*)(s + lo + 4);
  bf16x8 v;
  v[0]=(short)f2bf(a.x); v[1]=(short)f2bf(a.y); v[2]=(short)f2bf(a.z); v[3]=(short)f2bf(a.w);
  v[4]=(short)f2bf(b.x); v[5]=(short)f2bf(b.y); v[6]=(short)f2bf(b.z); v[7]=(short)f2bf(b.w);
  *(bf16x8*)(d + i) = v;
}

// ------------------------------------------------- encoder layer1 (3->128)
__global__ __launch_bounds__(256) void enc1_kernel(
    const float* __restrict__ neighC,
    const float* __restrict__ w1, const float* __restrict__ b1,
    const float* __restrict__ g1, const float* __restrict__ be1,
    unsigned short* __restrict__ f1c)
{
  const int t = threadIdx.x;
  const int r = blockIdx.x*2 + (t >> 7);
  const int c = t & 127;
  const float* nr = neighC + (size_t)r*3;
  float x0 = nr[0], x1 = nr[1], x2 = nr[2];
  float s = x0*w1[3*c] + x1*w1[3*c+1] + x2*w1[3*c+2] + b1[c];
  float v = fmaxf(s*g1[c] + be1[c], 0.0f);
  f1c[(size_t)r*128 + c] = f2bf(v);
}

// ------------------------------------------------- encoder fg pool (layer2 max)
__global__ __launch_bounds__(256) void pool2_kernel(
    const unsigned short* __restrict__ f2c, unsigned short* __restrict__ fgc)
{
  const int g = blockIdx.x, c = threadIdx.x;
  float mx = -3.0e38f;
  #pragma unroll 8
  for (int m = 0; m < kM; ++m)
    mx = fmaxf(mx, bf2f(f2c[((size_t)g*kM + m)*256 + c]));
  fgc[(size_t)g*256 + c] = f2bf(mx);
}

// ------------------------------------------------------------- MFMA GEMM
// Out[M,N] (+epilogue) = A[M,K](bf16,lda) @ B[N,K](bf16,ldb)^T
// Block tile BMxBN (BM=FM*32, BN=FN*32); BK=64; 256 thr = 4 waves (2x2).
// EPI: 0 bf16 plain | 1 bf16 +bias | 2 f32 +bias | 3 bf16 relu((v+base[r>>5])*g+be)
//      4 fused 32-row max-pool (+bias) -> tokens (FM==2) | 5 f32 res+v+bias | 6 bf16 gelu(v+bias)
template <int EPI, int FM, int FN>
__global__ __launch_bounds__(256) void mgemm_kernel(
    const unsigned short* __restrict__ A, int lda,
    const unsigned short* __restrict__ Bb, int ldb,
    void* __restrict__ Cv,
    const float* __restrict__ bias,
    const float* __restrict__ aux,       // res (EPI5) or base (EPI3)
    const float* __restrict__ gsc, const float* __restrict__ bsc,  // EPI3
    int Mm, int Nn, int Kk,
    float* __restrict__ poolOut, int poolG0)
{
  constexpr int BM = FM*32, BN = FN*32;
  __shared__ unsigned short As[BM][72];
  __shared__ unsigned short Bs[BN][72];
  const int t = threadIdx.x;
  const int m0 = blockIdx.x * BM;
  const int n0 = blockIdx.y * BN;
  const int w = t >> 6, lane = t & 63;
  const int wm = w >> 1, wn = w & 1;
  const int lr = lane & 15;
  const int lk = (lane >> 4) * 8;
  const int srow = t >> 3;          // 0..31
  const int skseg = (t & 7) * 8;    // 0..56
  f32x4 acc[FM][FN] = {};
  for (int k0 = 0; k0 < Kk; k0 += 64) {
    #pragma unroll
    for (int p = 0; p < BM/32; ++p) {
      int r = p*32 + srow;
      int gr = m0 + r;
      bf16x8 av = {};
      if (gr < Mm) av = *(const bf16x8*)(A + (size_t)gr*lda + k0 + skseg);
      *(bf16x8*)(&As[r][skseg]) = av;
    }
    #pragma unroll
    for (int p = 0; p < BN/32; ++p) {
      int r = p*32 + srow;
      bf16x8 bv = *(const bf16x8*)(Bb + (size_t)(n0 + r)*ldb + k0 + skseg);
      *(bf16x8*)(&Bs[r][skseg]) = bv;
    }
    __syncthreads();
    #pragma unroll
    for (int kk = 0; kk < 64; kk += 32) {
      bf16x8 af[FM], bf[FN];
      #pragma unroll
      for (int i = 0; i < FM; ++i)
        af[i] = *(const bf16x8*)(&As[wm*(FM*16) + i*16 + lr][kk + lk]);
      #pragma unroll
      for (int i = 0; i < FN; ++i)
        bf[i] = *(const bf16x8*)(&Bs[wn*(FN*16) + i*16 + lr][kk + lk]);
      #pragma unroll
      for (int i = 0; i < FM; ++i)
        #pragma unroll
        for (int j = 0; j < FN; ++j)
          acc[i][j] = __builtin_amdgcn_mfma_f32_16x16x32_bf16(af[i], bf[j], acc[i][j], 0, 0, 0);
    }
    __syncthreads();
  }

  if constexpr (EPI == 4) {
    // fused max-pool over the wave's 32-row group (FM==2, Mm%64==0)
    #pragma unroll
    for (int ni = 0; ni < FN; ++ni) {
      int cc = n0 + wn*(FN*16) + ni*16 + lr;
      float mx = -3.0e38f;
      #pragma unroll
      for (int mi = 0; mi < FM; ++mi)
        #pragma unroll
        for (int j = 0; j < 4; ++j)
          mx = fmaxf(mx, acc[mi][ni][j]);
      mx = fmaxf(mx, __shfl_xor(mx, 16));
      mx = fmaxf(mx, __shfl_xor(mx, 32));
      if ((lane >> 4) == 0) {
        int ggl = poolG0 + (m0 >> 5) + wm;
        int b = ggl >> 7, g = ggl & 127;
        poolOut[((size_t)b*kNT + 1 + g)*kC + cc] = mx + bias[cc];
      }
    }
    return;
  }

  #pragma unroll
  for (int mi = 0; mi < FM; ++mi) {
    #pragma unroll
    for (int j = 0; j < 4; ++j) {
      int r = m0 + wm*(FM*16) + mi*16 + (lane >> 4)*4 + j;
      if (r < Mm) {
        #pragma unroll
        for (int ni = 0; ni < FN; ++ni) {
          int cc = n0 + wn*(FN*16) + ni*16 + lr;
          float v = acc[mi][ni][j];
          size_t o = (size_t)r*Nn + cc;
          if constexpr (EPI == 0) {
            ((unsigned short*)Cv)[o] = f2bf(v);
          } else if constexpr (EPI == 1) {
            ((unsigned short*)Cv)[o] = f2bf(v + bias[cc]);
          } else if constexpr (EPI == 2) {
            ((float*)Cv)[o] = v + bias[cc];
          } else if constexpr (EPI == 3) {
            float u = (v + aux[(size_t)(r >> 5)*Nn + cc])*gsc[cc] + bsc[cc];
            ((unsigned short*)Cv)[o] = f2bf(fmaxf(u, 0.0f));
          } else if constexpr (EPI == 5) {
            ((float*)Cv)[o] = aux[o] + v + bias[cc];
          } else {
            float u = v + bias[cc];
            ((unsigned short*)Cv)[o] = f2bf(0.5f*u*(1.0f + erff(u*0.70710678118654752440f)));
          }
        }
      }
    }
  }
}

// ----------------------------------------------------------- CLS token init
__global__ void cls_kernel(const float* __restrict__ ct, const float* __restrict__ cp,
                           float* __restrict__ x)
{
  int idx = blockIdx.x*256 + threadIdx.x;
  if (idx >= kB*kC) return;
  int b = idx / kC, c = idx % kC;
  x[(size_t)b*kNT*kC + c] = ct[c] + cp[c];
}

// ------------------------------------------------------------- LayerNorm
template <int OUTBF>
__global__ __launch_bounds__(256) void ln_kernel(
    const float* __restrict__ in, void* __restrict__ outv,
    const float* __restrict__ g, const float* __restrict__ bb)
{
  const int t = threadIdx.x;
  const int lane = t & 63;
  const int row = blockIdx.x*4 + (t >> 6);
  const float* p = in + (size_t)row*kC;
  float v[6];
  #pragma unroll
  for (int k = 0; k < 6; ++k) v[k] = p[k*64 + lane];
  float s = 0.f;
  #pragma unroll
  for (int k = 0; k < 6; ++k) s += v[k];
  #pragma unroll
  for (int off = 1; off < 64; off <<= 1) s += __shfl_xor(s, off);
  float mean = s / 384.0f;
  float vs = 0.f;
  #pragma unroll
  for (int k = 0; k < 6; ++k) { float d = v[k]-mean; vs += d*d; }
  #pragma unroll
  for (int off = 1; off < 64; off <<= 1) vs += __shfl_xor(vs, off);
  float r = rsqrtf(vs / 384.0f + 1e-5f);
  #pragma unroll
  for (int k = 0; k < 6; ++k) {
    int c = k*64 + lane;
    float o = (v[k]-mean)*r*g[c] + bb[c];
    if constexpr (OUTBF) ((unsigned short*)outv)[(size_t)row*kC + c] = f2bf(o);
    else                 ((float*)outv)[(size_t)row*kC + c] = o;
  }
}

// ------------------------------------------------------------- attention
// One block per (b,h), 512 thr (VGPR 128, no spill — the r10 1024-thr
// version spilled q[12] at VGPR=64: FETCH 12MB->449MB, attn 161us).
// V stored TRANSPOSED in LDS: vt[d][j] so PV's inner loop is 33 float4
// reads per row instead of 512 scalar b32 column reads (the measured
// bottleneck: LDS issue-count-bound). vt rows padded to 132 (16B-aligned).
// Multiply-add order per accumulator identical -> bit-exact.
__global__ __launch_bounds__(512) void attn_kernel(
    const unsigned short* __restrict__ qkv, const float* __restrict__ pcs,
    const float* __restrict__ psn, const float* __restrict__ gth,
    unsigned short* __restrict__ o)
{
  __shared__ float qs[kNT][kHD];
  __shared__ float ks[kNT][52];
  __shared__ float vt[kHD][132];
  __shared__ float gcs[24], gss[24];
  __shared__ float ps[8][132];
  const int t = threadIdx.x;
  const int bh = blockIdx.x;
  const int b = bh >> 3, hh = bh & 7;
  if (t < 24) { float th = gth[hh*24 + t]; gcs[t] = cosf(th); gss[t] = sinf(th); }
  __syncthreads();
  for (int idx = t; idx < kNT*24; idx += 512) {
    int n = idx / 24, p = idx % 24;
    const unsigned short* base = qkv + ((size_t)(b*kNT + n))*1152 + hh*kHD + 2*p;
    float q0 = bf2f(base[0]),   q1 = bf2f(base[1]);
    float k0 = bf2f(base[384]), k1 = bf2f(base[385]);
    float v0 = bf2f(base[768]), v1 = bf2f(base[769]);
    float cg = gcs[p], sg = gss[p];
    float qr = q0*cg - q1*sg, qi = q0*sg + q1*cg;
    float kr = k0*cg - k1*sg, ki = k0*sg + k1*cg;
    if (n > 0) {
      size_t pi = ((size_t)b*kG + (n-1))*24 + p;
      float pc = pcs[pi], pv = psn[pi];
      float tq = qr*pc - qi*pv; qi = qr*pv + qi*pc; qr = tq;
      float tk = kr*pc - ki*pv; ki = kr*pv + ki*pc; kr = tk;
    }
    qs[n][2*p] = qr; qs[n][2*p+1] = qi;
    ks[n][2*p] = kr; ks[n][2*p+1] = ki;
    vt[2*p][n] = v0; vt[2*p+1][n] = v1;
  }
  __syncthreads();
  const int lane = t & 63, w = t >> 6;
  for (int r = w; r < kNT; r += 8) {
    float4 q[12];
    #pragma unroll
    for (int d = 0; d < 12; ++d) q[d] = *(const float4*)(&qs[r][d*4]);
    float sv[3];
    float mx = -3.0e38f;
    #pragma unroll
    for (int ji = 0; ji < 3; ++ji) {
      int j = ji*64 + lane;
      float s = -3.0e38f;
      if (j < kNT) {
        float a0 = 0.f, a1 = 0.f;
        #pragma unroll
        for (int d = 0; d < 12; d += 2) {
          float4 k0v = *(const float4*)(&ks[j][d*4]);
          float4 k1v = *(const float4*)(&ks[j][d*4+4]);
          a0 += q[d].x*k0v.x + q[d].y*k0v.y + q[d].z*k0v.z + q[d].w*k0v.w;
          a1 += q[d+1].x*k1v.x + q[d+1].y*k1v.y + q[d+1].z*k1v.z + q[d+1].w*k1v.w;
        }
        s = (a0 + a1) * 0.14433756729740643f;
      }
      sv[ji] = s;
      mx = fmaxf(mx, s);
    }
    #pragma unroll
    for (int off = 1; off < 64; off <<= 1) mx = fmaxf(mx, __shfl_xor(mx, off));
    float sum = 0.f;
    #pragma unroll
    for (int ji = 0; ji < 3; ++ji) {
      int j = ji*64 + lane;
      if (j < kNT) { float e = expf(sv[ji] - mx); ps[w][j] = e; sum += e; }
    }
    #pragma unroll
    for (int off = 1; off < 64; off <<= 1) sum += __shfl_xor(sum, off);
    if (lane < kHD) {
      float ac0 = 0.f, ac1 = 0.f, ac2 = 0.f, ac3 = 0.f;
      for (int j4 = 0; j4 < 128; j4 += 16) {
        float4 p0 = *(const float4*)(&ps[w][j4]);
        float4 p1 = *(const float4*)(&ps[w][j4+4]);
        float4 p2 = *(const float4*)(&ps[w][j4+8]);
        float4 p3 = *(const float4*)(&ps[w][j4+12]);
        float4 v0 = *(const float4*)(&vt[lane][j4]);
        float4 v1 = *(const float4*)(&vt[lane][j4+4]);
        float4 v2 = *(const float4*)(&vt[lane][j4+8]);
        float4 v3 = *(const float4*)(&vt[lane][j4+12]);
        ac0 += p0.x*v0.x + p0.y*v0.y + p0.z*v0.z + p0.w*v0.w;
        ac1 += p1.x*v1.x + p1.y*v1.y + p1.z*v1.z + p1.w*v1.w;
        ac2 += p2.x*v2.x + p2.y*v2.y + p2.z*v2.z + p2.w*v2.w;
        ac3 += p3.x*v3.x + p3.y*v3.y + p3.z*v3.z + p3.w*v3.w;
      }
      float accv = ((ac0 + ac1) + (ac2 + ac3)) + ps[w][128]*vt[lane][128];
      o[((size_t)(b*kNT + r))*kC + hh*kHD + lane] = f2bf(accv / sum);
    }
  }
}

// ------------------------------------------------------------- head
__global__ __launch_bounds__(256) void head_kernel(
    const float* __restrict__ xf,
    const float* __restrict__ hw1, const float* __restrict__ hb1,
    const float* __restrict__ hg1, const float* __restrict__ hbe1,
    const float* __restrict__ hw2, const float* __restrict__ hb2,
    const float* __restrict__ hg2, const float* __restrict__ hbe2,
    const float* __restrict__ hw3, const float* __restrict__ hb3,
    float* __restrict__ out)
{
  __shared__ float f[768];
  __shared__ float h1[256], h2[256];
  const int t = threadIdx.x;
  const int b = blockIdx.x;
  const float* xb = xf + (size_t)b*kNT*kC;
  for (int c = t; c < kC; c += 256) {
    f[c] = xb[c];
    float mx = -3.0e38f;
    for (int n = 1; n < kNT; ++n) mx = fmaxf(mx, xb[(size_t)n*kC + c]);
    f[kC + c] = mx;
  }
  __syncthreads();
  {
    float acc = hb1[t];
    for (int k = 0; k < 768; k += 4) {
      float4 wv = *(const float4*)(hw1 + (size_t)t*768 + k);
      float4 fv = *(const float4*)(&f[k]);
      acc += fv.x*wv.x + fv.y*wv.y + fv.z*wv.z + fv.w*wv.w;
    }
    h1[t] = fmaxf(acc*hg1[t] + hbe1[t], 0.0f);
  }
  __syncthreads();
  {
    float acc = hb2[t];
    for (int k = 0; k < 256; k += 4) {
      float4 wv = *(const float4*)(hw2 + (size_t)t*256 + k);
      float4 fv = *(const float4*)(&h1[k]);
      acc += fv.x*wv.x + fv.y*wv.y + fv.z*wv.z + fv.w*wv.w;
    }
    h2[t] = fmaxf(acc*hg2[t] + hbe2[t], 0.0f);
  }
  __syncthreads();
  if (t < 40) {
    float acc = hb3[t];
    for (int k = 0; k < 256; k += 4) {
      float4 wv = *(const float4*)(hw3 + (size_t)t*256 + k);
      float4 fv = *(const float4*)(&h2[k]);
      acc += fv.x*wv.x + fv.y*wv.y + fv.z*wv.z + fv.w*wv.w;
    }
    out[(size_t)b*40 + t] = acc;
  }
}

// ------------------------------------------------------------- launch
extern "C" void kernel_launch(void* const* d_in, const int* in_sizes, int n_in,
                              void* d_out, int out_size, void* d_ws, size_t ws_size,
                              hipStream_t stream) {
  const float* pts     = (const float*)d_in[0];
  const float* enc_w1  = (const float*)d_in[1];
  const float* enc_b1  = (const float*)d_in[2];
  const float* enc_g1  = (const float*)d_in[3];
  const float* enc_be1 = (const float*)d_in[4];
  const float* enc_w2  = (const float*)d_in[5];
  const float* enc_b2  = (const float*)d_in[6];
  const float* enc_w3  = (const float*)d_in[7];
  const float* enc_b3  = (const float*)d_in[8];
  const float* enc_g2  = (const float*)d_in[9];
  const float* enc_be2 = (const float*)d_in[10];
  const float* enc_w4  = (const float*)d_in[11];
  const float* enc_b4  = (const float*)d_in[12];
  const float* cls_tok = (const float*)d_in[13];
  const float* cls_pos = (const float*)d_in[14];
  const float* ln1_g   = (const float*)d_in[15];
  const float* ln1_b   = (const float*)d_in[16];
  const float* qkv_w   = (const float*)d_in[17];
  const float* givens  = (const float*)d_in[18];
  const float* proj_w  = (const float*)d_in[19];
  const float* proj_b  = (const float*)d_in[20];
  const float* ln2_g   = (const float*)d_in[21];
  const float* ln2_b   = (const float*)d_in[22];
  const float* fc1_w   = (const float*)d_in[23];
  const float* fc1_b   = (const float*)d_in[24];
  const float* fc2_w   = (const float*)d_in[25];
  const float* fc2_b   = (const float*)d_in[26];
  const float* norm_g  = (const float*)d_in[27];
  const float* norm_b  = (const float*)d_in[28];
  const float* hw1     = (const float*)d_in[29];
  const float* hb1     = (const float*)d_in[30];
  const float* hg1     = (const float*)d_in[31];
  const float* hbe1    = (const float*)d_in[32];
  const float* hw2     = (const float*)d_in[33];
  const float* hb2     = (const float*)d_in[34];
  const float* hg2     = (const float*)d_in[35];
  const float* hbe2    = (const float*)d_in[36];
  const float* hw3     = (const float*)d_in[37];
  const float* hb3     = (const float*)d_in[38];

  constexpr size_t kWL = 1769472ull;          // per-layer bf16 weight elements
  char* wsb = (char*)d_ws;
  size_t off = 0;
  float* center = (float*)(wsb + off); off += (size_t)kB*kG*3*4;
  float* pcs    = (float*)(wsb + off); off += (size_t)kB*kG*24*4;
  float* psn    = (float*)(wsb + off); off += (size_t)kB*kG*24*4;
  float* neigh  = (float*)(wsb + off); off += (size_t)kB*kG*kM*3*4;
  float* xbuf   = (float*)(wsb + off); off += (size_t)kRows*kC*4;
  unsigned short* encwb = (unsigned short*)(wsb + off); off += 491520ull*2;
  unsigned short* wlbf  = (unsigned short*)(wsb + off);
  const size_t scratchNeed = 16777216ull + 8388608ull + 262144ull + 1048576ull;
  const bool bigws = ws_size >= off + 12*kWL*2 + scratchNeed;
  off += (bigws ? 12*kWL*2 : kWL*2);
  char* scratch = wsb + off;
  // encoder view of scratch (f1c aliases f3c region: disjoint lifetimes)
  unsigned short* f3c   = (unsigned short*)(scratch);
  unsigned short* f1c   = (unsigned short*)(scratch);
  unsigned short* f2c   = (unsigned short*)(scratch + 16777216);
  unsigned short* fgc   = (unsigned short*)(scratch + 16777216 + 8388608);
  float*          basec = (float*)(scratch + 16777216 + 8388608 + 262144);
  // transformer view of scratch (hbuf + qkvb + attnob; mlpb aliases)
  unsigned short* hbuf   = (unsigned short*)(scratch);
  unsigned short* qkvb   = (unsigned short*)(scratch + 3170304);
  unsigned short* attnob = (unsigned short*)(scratch + 3170304 + 9510912);
  unsigned short* mlpb   = (unsigned short*)(scratch + 3170304);
  float*          flnb   = (float*)(scratch + 3170304);  // post-loop, qkvb dead

  const unsigned short* encw2 = encwb;
  const unsigned short* encw3 = encwb + 32768;
  const unsigned short* encw4 = encwb + 32768 + 262144;

  fps_kernel<<<kB, 128, 0, stream>>>(pts, center);
  rope_kernel<<<(kB*kG*24 + 255)/256, 256, 0, stream>>>(center, pcs, psn);
  knn_kernel<<<kB*kG/4, 256, 0, stream>>>(pts, center, neigh);

  // weight caches
  wcvt_kernel<<<32768/8/256, 256, 0, stream>>>(enc_w2, (unsigned short*)encw2, 32768);
  wcvt_kernel<<<262144/8/256, 256, 0, stream>>>(enc_w3, (unsigned short*)encw3, 262144);
  wcvt_kernel<<<196608/8/256, 256, 0, stream>>>(enc_w4, (unsigned short*)encw4, 196608);
  if (bigws) {
    for (int l = 0; l < 12; ++l)
      wcvt4_kernel<<<864, 256, 0, stream>>>(
          qkv_w + (size_t)l*442368, proj_w + (size_t)l*147456,
          fc1_w + (size_t)l*589824, fc2_w + (size_t)l*589824, wlbf + (size_t)l*kWL);
  }

  // ---- encoder: 8 chunks of 512 groups (16384 rows) ----
  for (int c = 0; c < 8; ++c) {
    const float* nc = neigh + (size_t)c*kRC*3;
    enc1_kernel<<<kRC/2, 256, 0, stream>>>(nc, enc_w1, enc_b1, enc_g1, enc_be1, f1c);
    mgemm_kernel<1,2,2><<<dim3(kRC/64, 4), 256, 0, stream>>>(
        f1c, 128, encw2, 128, f2c, enc_b2, nullptr, nullptr, nullptr,
        kRC, 256, 128, nullptr, 0);
    pool2_kernel<<<kGC, 256, 0, stream>>>(f2c, fgc);
    mgemm_kernel<2,2,2><<<dim3(kGC/64, 8), 256, 0, stream>>>(
        fgc, 256, encw3, 512, basec, enc_b3, nullptr, nullptr, nullptr,
        kGC, 512, 256, nullptr, 0);
    mgemm_kernel<3,2,2><<<dim3(kRC/64, 8), 256, 0, stream>>>(
        f2c, 256, encw3 + 256, 512, f3c, nullptr, basec, enc_g2, enc_be2,
        kRC, 512, 256, nullptr, 0);
    mgemm_kernel<4,2,2><<<dim3(kRC/64, 6), 256, 0, stream>>>(
        f3c, 512, encw4, 512, nullptr, enc_b4, nullptr, nullptr, nullptr,
        kRC, 384, 512, xbuf, c*kGC);
  }
  cls_kernel<<<(kB*kC + 255)/256, 256, 0, stream>>>(cls_tok, cls_pos, xbuf);

  const int lnGrid = kRows/4;
  for (int l = 0; l < 12; ++l) {
    unsigned short* wl = wlbf + (bigws ? (size_t)l*kWL : 0);
    if (!bigws)
      wcvt4_kernel<<<864, 256, 0, stream>>>(
          qkv_w + (size_t)l*442368, proj_w + (size_t)l*147456,
          fc1_w + (size_t)l*589824, fc2_w + (size_t)l*589824, wl);
    const unsigned short* wq  = wl;
    const unsigned short* wp  = wl + 442368;
    const unsigned short* w1f = wl + 589824;
    const unsigned short* w2f = wl + 1179648;
    ln_kernel<1><<<lnGrid, 256, 0, stream>>>(xbuf, hbuf, ln1_g + l*kC, ln1_b + l*kC);
    mgemm_kernel<0,2,2><<<dim3(65, 18), 256, 0, stream>>>(
        hbuf, kC, wq, kC, qkvb, nullptr, nullptr, nullptr, nullptr,
        kRows, 1152, kC, nullptr, 0);
    attn_kernel<<<kB*kH, 512, 0, stream>>>(qkvb, pcs, psn, givens + (size_t)l*kH*24, attnob);
    mgemm_kernel<5,2,2><<<dim3(65, 6), 256, 0, stream>>>(
        attnob, kC, wp, kC, xbuf, proj_b + l*kC, xbuf, nullptr, nullptr,
        kRows, kC, kC, nullptr, 0);
    ln_kernel<1><<<lnGrid, 256, 0, stream>>>(xbuf, hbuf, ln2_g + l*kC, ln2_b + l*kC);
    mgemm_kernel<6,2,2><<<dim3(65, 24), 256, 0, stream>>>(
        hbuf, kC, w1f, kC, mlpb, fc1_b + l*kMLP, nullptr, nullptr, nullptr,
        kRows, kMLP, kC, nullptr, 0);
    mgemm_kernel<5,2,2><<<dim3(65, 6), 256, 0, stream>>>(
        mlpb, kMLP, w2f, kMLP, xbuf, fc2_b + l*kC, xbuf, nullptr, nullptr,
        kRows, kC, kMLP, nullptr, 0);
  }
  ln_kernel<0><<<lnGrid, 256, 0, stream>>>(xbuf, flnb, norm_g, norm_b);
  head_kernel<<<kB, 256, 0, stream>>>(flnb,
      hw1, hb1, hg1, hbe1, hw2, hb2, hg2, hbe2, hw3, hb3, (float*)d_out);
}